// Round 4
// baseline (325.240 us; speedup 1.0000x reference)
//
#include <hip/hip_runtime.h>
#include <math.h>

// B=64, N_in=1152, K_in=8, N_out=64, K_out=16, ITER=3
// u recomputed on the fly; logits via running Vsum; no atomics; no spills.
// 2 b per wave: halves LDS W-read traffic vs 1 b/wave (the round-3 bottleneck).

#define TI 18         // i's per chunk
#define NCHUNK 64     // 1152 / TI
// block: 256 threads = 4 waves, 2 b per wave -> 8 b per block; 8 b-groups.

__device__ __forceinline__ float wave_max64(float v) {
    #pragma unroll
    for (int d = 32; d >= 1; d >>= 1) v = fmaxf(v, __shfl_xor(v, d, 64));
    return v;
}
__device__ __forceinline__ float wave_sum64(float v) {
    #pragma unroll
    for (int d = 32; d >= 1; d >>= 1) v += __shfl_xor(v, d, 64);
    return v;
}

// Grid: 8 * NCHUNK = 512 blocks x 256 threads.
// wave w owns b = bblk*8 + w*2 + {0,1}; lane = o. Double-buffered W slice in LDS.
template<bool UNIFORM, bool DIRECT>
__global__ __launch_bounds__(256, 2)   // cap 256 VGPR: room for 2-b state, no spill
void caps_route(const float* __restrict__ x, const float* __restrict__ W,
                const float* __restrict__ Vsum, float* __restrict__ s_out) {
    __shared__ float4 wlds[2][2048];          // [buf][f=32][o=64], XOR-swizzled
    __shared__ float4 xlds[8 * TI * 2];       // x tile [b=8][TI][2]

    const int t = threadIdx.x;
    const int w = t >> 6;          // wave 0..3
    const int o = t & 63;
    const int chunk = blockIdx.x % NCHUNK;
    const int bblk  = blockIdx.x / NCHUNK;
    const int i0 = chunk * TI;
    const int bbase = bblk * 8 + w * 2;

    const float4* __restrict__ xg = (const float4*)x;
    const float4* __restrict__ Wg = (const float4*)W;

    // stage x tile: 8 b x TI x 2 = 288 float4
    for (int e = t; e < 8 * TI * 2; e += 256) {
        int bb = e / (TI * 2), r = e % (TI * 2);
        xlds[e] = xg[((bblk * 8 + bb) * 1152 + i0 + (r >> 1)) * 2 + (r & 1)];
    }

    float vsf[2][16];
    if (!UNIFORM) {
        const float4* vg = (const float4*)Vsum;
        #pragma unroll
        for (int l = 0; l < 2; ++l) {
            #pragma unroll
            for (int q = 0; q < 4; ++q) {
                float4 v = vg[((size_t)(bbase + l) * 64 + o) * 4 + q];
                vsf[l][q*4+0] = v.x; vsf[l][q*4+1] = v.y;
                vsf[l][q*4+2] = v.z; vsf[l][q*4+3] = v.w;
            }
        }
    }

    float sacc[2][16];
    #pragma unroll
    for (int l = 0; l < 2; ++l)
        #pragma unroll
        for (int k = 0; k < 16; ++k) sacc[l][k] = 0.0f;

    // prologue: stage slice 0 into buf 0 (8 float4/thread)
    float4 wr[8];
    {
        const float4* Wi = Wg + (size_t)i0 * 32;
        #pragma unroll
        for (int r = 0; r < 8; ++r) {
            int idx = r * 256 + t;
            wr[r] = Wi[(size_t)(idx >> 5) * 36864 + (idx & 31)];
        }
        #pragma unroll
        for (int r = 0; r < 8; ++r) {
            int idx = r * 256 + t;
            wlds[0][(idx & 31) * 64 + ((idx >> 5) ^ (idx & 7))] = wr[r];
        }
    }

    for (int ii = 0; ii < TI; ++ii) {
        const int cur = ii & 1;
        __syncthreads();   // buf[cur] writes (prev iter / prologue) + x stage visible

        // issue next slice's global loads early; latency hides under compute
        if (ii + 1 < TI) {
            const float4* Wi = Wg + (size_t)(i0 + ii + 1) * 32;
            #pragma unroll
            for (int r = 0; r < 8; ++r) {
                int idx = r * 256 + t;
                wr[r] = Wi[(size_t)(idx >> 5) * 36864 + (idx & 31)];
            }
        }

        float4 xa0 = xlds[(w*2+0) * (TI*2) + ii*2 + 0];   // wave-uniform broadcast
        float4 xb0 = xlds[(w*2+0) * (TI*2) + ii*2 + 1];
        float4 xa1 = xlds[(w*2+1) * (TI*2) + ii*2 + 0];
        float4 xb1 = xlds[(w*2+1) * (TI*2) + ii*2 + 1];

        const float4* wb = wlds[cur];
        float u[2][16];
        float logit0 = 0.0f, logit1 = 0.0f;
        #pragma unroll
        for (int k = 0; k < 16; ++k) {
            const int f0 = 2 * k, f1 = 2 * k + 1;
            float4 w0 = wb[f0 * 64 + (o ^ (f0 & 7))];   // conflict-free b128
            float4 w1 = wb[f1 * 64 + (o ^ (f1 & 7))];
            float uk0 = w0.x * xa0.x;
            uk0 = fmaf(w0.y, xa0.y, uk0); uk0 = fmaf(w0.z, xa0.z, uk0);
            uk0 = fmaf(w0.w, xa0.w, uk0); uk0 = fmaf(w1.x, xb0.x, uk0);
            uk0 = fmaf(w1.y, xb0.y, uk0); uk0 = fmaf(w1.z, xb0.z, uk0);
            uk0 = fmaf(w1.w, xb0.w, uk0);
            float uk1 = w0.x * xa1.x;
            uk1 = fmaf(w0.y, xa1.y, uk1); uk1 = fmaf(w0.z, xa1.z, uk1);
            uk1 = fmaf(w0.w, xa1.w, uk1); uk1 = fmaf(w1.x, xb1.x, uk1);
            uk1 = fmaf(w1.y, xb1.y, uk1); uk1 = fmaf(w1.z, xb1.z, uk1);
            uk1 = fmaf(w1.w, xb1.w, uk1);
            u[0][k] = uk0; u[1][k] = uk1;
            if (!UNIFORM) {
                logit0 = fmaf(vsf[0][k], uk0, logit0);
                logit1 = fmaf(vsf[1][k], uk1, logit1);
            }
        }

        float c0, c1;
        if (UNIFORM) {
            c0 = c1 = 1.0f / 64.0f;
        } else {
            // two independent 64-lane butterflies (ILP-friendly)
            float m0 = logit0, m1 = logit1;
            #pragma unroll
            for (int d = 32; d >= 1; d >>= 1) {
                m0 = fmaxf(m0, __shfl_xor(m0, d, 64));
                m1 = fmaxf(m1, __shfl_xor(m1, d, 64));
            }
            float e0 = __expf(logit0 - m0);
            float e1 = __expf(logit1 - m1);
            float s0 = e0, s1 = e1;
            #pragma unroll
            for (int d = 32; d >= 1; d >>= 1) {
                s0 += __shfl_xor(s0, d, 64);
                s1 += __shfl_xor(s1, d, 64);
            }
            c0 = e0 / s0;
            c1 = e1 / s1;
        }

        #pragma unroll
        for (int k = 0; k < 16; ++k) {
            sacc[0][k] = fmaf(c0, u[0][k], sacc[0][k]);
            sacc[1][k] = fmaf(c1, u[1][k], sacc[1][k]);
        }

        // write next slice into the other buffer
        if (ii + 1 < TI) {
            #pragma unroll
            for (int r = 0; r < 8; ++r) {
                int idx = r * 256 + t;
                wlds[cur ^ 1][(idx & 31) * 64 + ((idx >> 5) ^ (idx & 7))] = wr[r];
            }
        }
    }

    if (DIRECT) {
        // private chunk slot [chunk][b][o][k], plain coalesced stores
        #pragma unroll
        for (int l = 0; l < 2; ++l) {
            float4* sp = (float4*)s_out + (((size_t)chunk * 64 + (bbase + l)) * 64 + o) * 4;
            sp[0] = make_float4(sacc[l][0],  sacc[l][1],  sacc[l][2],  sacc[l][3]);
            sp[1] = make_float4(sacc[l][4],  sacc[l][5],  sacc[l][6],  sacc[l][7]);
            sp[2] = make_float4(sacc[l][8],  sacc[l][9],  sacc[l][10], sacc[l][11]);
            sp[3] = make_float4(sacc[l][12], sacc[l][13], sacc[l][14], sacc[l][15]);
        }
    } else {
        #pragma unroll
        for (int l = 0; l < 2; ++l) {
            float* sp = s_out + ((size_t)(bbase + l) * 64 + o) * 16;
            #pragma unroll
            for (int k = 0; k < 16; ++k) atomicAdd(sp + k, sacc[l][k]);
        }
    }
}

// Reduce NCHUNK chunk-partials per (b,o), then squash.
// MODE 0: Vsum=v; 1: Vsum+=v; 2: out=v.
template<int MODE>
__global__ __launch_bounds__(256)
void reduce_squash(const float* __restrict__ sp, float* __restrict__ Vs, float* __restrict__ out) {
    const int t = threadIdx.x;
    const int p = t >> 4;          // pair 0..15
    const int q = t & 15;          // chunk group 0..15 (NCHUNK/16 each)
    const int pair = blockIdx.x * 16 + p;
    const int b = pair >> 6, o = pair & 63;

    float acc[16];
    #pragma unroll
    for (int k = 0; k < 16; ++k) acc[k] = 0.0f;

    const float4* base = (const float4*)sp;
    for (int c = q * (NCHUNK/16); c < (q + 1) * (NCHUNK/16); ++c) {
        const float4* pptr = base + (((size_t)c * 64 + b) * 64 + o) * 4;
        float4 v0 = pptr[0], v1 = pptr[1], v2 = pptr[2], v3 = pptr[3];
        acc[0] += v0.x; acc[1] += v0.y; acc[2]  += v0.z; acc[3]  += v0.w;
        acc[4] += v1.x; acc[5] += v1.y; acc[6]  += v1.z; acc[7]  += v1.w;
        acc[8] += v2.x; acc[9] += v2.y; acc[10] += v2.z; acc[11] += v2.w;
        acc[12] += v3.x; acc[13] += v3.y; acc[14] += v3.z; acc[15] += v3.w;
    }

    #pragma unroll
    for (int d = 1; d < 16; d <<= 1) {
        #pragma unroll
        for (int k = 0; k < 16; ++k) acc[k] += __shfl_xor(acc[k], d, 64);
    }

    if (q == 0) {
        float n2 = 0.0f;
        #pragma unroll
        for (int k = 0; k < 16; ++k) n2 = fmaf(acc[k], acc[k], n2);
        const float scale = n2 / (1.0f + n2) / sqrtf(n2 + 1e-7f);

        if (MODE == 0) {
            float4* vf = (float4*)Vs + (size_t)pair * 4;
            #pragma unroll
            for (int r = 0; r < 4; ++r)
                vf[r] = make_float4(scale * acc[r*4+0], scale * acc[r*4+1],
                                    scale * acc[r*4+2], scale * acc[r*4+3]);
        } else if (MODE == 1) {
            float4* vf = (float4*)Vs + (size_t)pair * 4;
            #pragma unroll
            for (int r = 0; r < 4; ++r) {
                float4 v = vf[r];
                v.x = fmaf(scale, acc[r*4+0], v.x); v.y = fmaf(scale, acc[r*4+1], v.y);
                v.z = fmaf(scale, acc[r*4+2], v.z); v.w = fmaf(scale, acc[r*4+3], v.w);
                vf[r] = v;
            }
        } else {
            float4* of = (float4*)out + (size_t)pair * 4;
            #pragma unroll
            for (int r = 0; r < 4; ++r)
                of[r] = make_float4(scale * acc[r*4+0], scale * acc[r*4+1],
                                    scale * acc[r*4+2], scale * acc[r*4+3]);
        }
    }
}

// Fallback squash for the atomic path.
template<int MODE>
__global__ __launch_bounds__(256)
void squash_k(float* __restrict__ s, float* __restrict__ Vsum, float* __restrict__ out) {
    const int t = blockIdx.x * blockDim.x + threadIdx.x;
    float4* sf = (float4*)s + t * 4;
    float4 qv[4];
    #pragma unroll
    for (int r = 0; r < 4; ++r) qv[r] = sf[r];
    float n2 = 0.0f;
    #pragma unroll
    for (int r = 0; r < 4; ++r)
        n2 = fmaf(qv[r].x, qv[r].x, fmaf(qv[r].y, qv[r].y, fmaf(qv[r].z, qv[r].z, fmaf(qv[r].w, qv[r].w, n2))));
    const float scale = n2 / (1.0f + n2) / sqrtf(n2 + 1e-7f);

    if (MODE == 0 || MODE == 1) {
        float4* vf = (float4*)Vsum + t * 4;
        #pragma unroll
        for (int r = 0; r < 4; ++r) {
            float4 v = (MODE == 1) ? vf[r] : make_float4(0.f, 0.f, 0.f, 0.f);
            v.x = fmaf(scale, qv[r].x, v.x); v.y = fmaf(scale, qv[r].y, v.y);
            v.z = fmaf(scale, qv[r].z, v.z); v.w = fmaf(scale, qv[r].w, v.w);
            vf[r] = v;
            sf[r] = make_float4(0.f, 0.f, 0.f, 0.f);
        }
    } else {
        float4* of = (float4*)out + t * 4;
        #pragma unroll
        for (int r = 0; r < 4; ++r)
            of[r] = make_float4(scale * qv[r].x, scale * qv[r].y, scale * qv[r].z, scale * qv[r].w);
    }
}

extern "C" void kernel_launch(void* const* d_in, const int* in_sizes, int n_in,
                              void* d_out, int out_size, void* d_ws, size_t ws_size,
                              hipStream_t stream) {
    const float* x = (const float*)d_in[0];   // [64,1152,8]
    const float* W = (const float*)d_in[1];   // [64,1152,16,8]
    float* out = (float*)d_out;               // [64,64,16]

    float* Vs = (float*)d_ws;                                  // 65536 floats
    float* sp = Vs + 65536;                                    // partials
    const size_t need = (65536ull + (size_t)NCHUNK * 64 * 64 * 16) * 4;

    dim3 grid(8 * NCHUNK), blk(256);

    if (ws_size >= need) {
        dim3 rg(256), rb(256);
        caps_route<true , true ><<<grid, blk, 0, stream>>>(x, W, nullptr, sp);
        reduce_squash<0><<<rg, rb, 0, stream>>>(sp, Vs, out);
        caps_route<false, true ><<<grid, blk, 0, stream>>>(x, W, Vs, sp);
        reduce_squash<1><<<rg, rb, 0, stream>>>(sp, Vs, out);
        caps_route<false, true ><<<grid, blk, 0, stream>>>(x, W, Vs, sp);
        reduce_squash<2><<<rg, rb, 0, stream>>>(sp, Vs, out);
    } else {
        float* s = sp;
        hipMemsetAsync(s, 0, 65536 * sizeof(float), stream);
        dim3 sg(16), sb(256);
        caps_route<true , false><<<grid, blk, 0, stream>>>(x, W, nullptr, s);
        squash_k<0><<<sg, sb, 0, stream>>>(s, Vs, out);
        caps_route<false, false><<<grid, blk, 0, stream>>>(x, W, Vs, s);
        squash_k<1><<<sg, sb, 0, stream>>>(s, Vs, out);
        caps_route<false, false><<<grid, blk, 0, stream>>>(x, W, Vs, s);
        squash_k<2><<<sg, sb, 0, stream>>>(s, Vs, out);
    }
}

// Round 5
// 187.231 us; speedup vs baseline: 1.7371x; 1.7371x over previous
//
#include <hip/hip_runtime.h>
#include <math.h>

// B=64, N_in=1152, K_in=8, N_out=64, K_out=16, ITER=3
// u recomputed on the fly; logits via running Vsum; no atomics.
// 2 b per wave (halves LDS W-traffic); W staged via global_load_lds DMA
// (no staging VGPRs); x held in SGPRs via readfirstlane -> ~110 live VGPRs.

#define TI 18         // i's per chunk
#define NCHUNK 64     // 1152 / TI

typedef const __attribute__((address_space(1))) unsigned int gu32;
typedef __attribute__((address_space(3))) unsigned int lu32;

__device__ __forceinline__ void load_lds16(const float4* g, float4* l) {
    // 16B per lane, dest = wave-uniform base + lane*16 (linear fill)
    __builtin_amdgcn_global_load_lds((gu32*)g, (lu32*)l, 16, 0, 0);
}
__device__ __forceinline__ float rfl(float v) {   // wave-uniform float -> SGPR
    return __builtin_bit_cast(float, __builtin_amdgcn_readfirstlane(__builtin_bit_cast(int, v)));
}

// Grid: 8 * NCHUNK = 512 blocks x 256 threads (4 waves).
// wave w owns b = bblk*8 + w*2 + {0,1}; lane = o.
// W slice in LDS: linear [f=32][o=64] float4, double-buffered.
template<bool UNIFORM, bool DIRECT>
__global__ __launch_bounds__(256, 2)
void caps_route(const float* __restrict__ x, const float* __restrict__ W,
                const float* __restrict__ Vsum, float* __restrict__ s_out) {
    __shared__ float4 wlds[2][2048];          // [buf][f][o], linear (DMA-filled)
    __shared__ float4 xlds[8 * TI * 2];       // x tile [b=8][TI][2]

    const int t = threadIdx.x;
    const int w = t >> 6;          // wave 0..3
    const int o = t & 63;
    const int chunk = blockIdx.x % NCHUNK;    // blocks sharing chunk differ by 64
    const int bblk  = blockIdx.x / NCHUNK;    //   in blockIdx -> same XCD (64%8==0)
    const int i0 = chunk * TI;
    const int bbase = bblk * 8 + w * 2;

    const float4* __restrict__ xg = (const float4*)x;
    const float4* __restrict__ Wg = (const float4*)W;

    // stage x tile: 8 b x TI x 2 = 288 float4, coalesced
    for (int e = t; e < 8 * TI * 2; e += 256) {
        int bb = e / (TI * 2), r = e % (TI * 2);
        xlds[e] = xg[((bblk * 8 + bb) * 1152 + i0 + (r >> 1)) * 2 + (r & 1)];
    }

    // per-lane W source: lane o supplies column o of each f-row.
    // wave w covers f = w*8 .. w*8+7.
    const float4* wsrc = Wg + (size_t)o * 36864 + (size_t)i0 * 32 + w * 8;

    // prologue: DMA slice 0 into buf 0
    #pragma unroll
    for (int r = 0; r < 8; ++r)
        load_lds16(wsrc + r, &wlds[0][(w * 8 + r) * 64]);

    float vsf[2][16];
    if (!UNIFORM) {
        const float4* vg = (const float4*)Vsum;
        #pragma unroll
        for (int l = 0; l < 2; ++l) {
            #pragma unroll
            for (int q = 0; q < 4; ++q) {
                float4 v = vg[((size_t)(bbase + l) * 64 + o) * 4 + q];
                vsf[l][q*4+0] = v.x; vsf[l][q*4+1] = v.y;
                vsf[l][q*4+2] = v.z; vsf[l][q*4+3] = v.w;
            }
        }
    }

    float sacc[2][16];
    #pragma unroll
    for (int l = 0; l < 2; ++l)
        #pragma unroll
        for (int k = 0; k < 16; ++k) sacc[l][k] = 0.0f;

    for (int ii = 0; ii < TI; ++ii) {
        const int cur = ii & 1;
        __syncthreads();   // implicit vmcnt(0): buf[cur] DMA complete; x visible

        // DMA next slice into the other buffer; overlaps with compute below
        if (ii + 1 < TI) {
            const float4* ws = wsrc + (size_t)(ii + 1) * 32;
            #pragma unroll
            for (int r = 0; r < 8; ++r)
                load_lds16(ws + r, &wlds[cur ^ 1][(w * 8 + r) * 64]);
        }

        // x for this slice -> SGPRs (wave-uniform broadcast reads)
        float4 A0 = xlds[(w*2+0) * (TI*2) + ii*2 + 0];
        float4 B0 = xlds[(w*2+0) * (TI*2) + ii*2 + 1];
        float4 A1 = xlds[(w*2+1) * (TI*2) + ii*2 + 0];
        float4 B1 = xlds[(w*2+1) * (TI*2) + ii*2 + 1];
        float xa0x = rfl(A0.x), xa0y = rfl(A0.y), xa0z = rfl(A0.z), xa0w = rfl(A0.w);
        float xb0x = rfl(B0.x), xb0y = rfl(B0.y), xb0z = rfl(B0.z), xb0w = rfl(B0.w);
        float xa1x = rfl(A1.x), xa1y = rfl(A1.y), xa1z = rfl(A1.z), xa1w = rfl(A1.w);
        float xb1x = rfl(B1.x), xb1y = rfl(B1.y), xb1z = rfl(B1.z), xb1w = rfl(B1.w);

        const float4* wb = wlds[cur];
        float u[2][16];
        float logit0 = 0.0f, logit1 = 0.0f;
        #pragma unroll
        for (int k = 0; k < 16; ++k) {
            float4 w0 = wb[(2*k  ) * 64 + o];   // coalesced b128, conflict-free
            float4 w1 = wb[(2*k+1) * 64 + o];
            float uk0 = w0.x * xa0x;
            uk0 = fmaf(w0.y, xa0y, uk0); uk0 = fmaf(w0.z, xa0z, uk0);
            uk0 = fmaf(w0.w, xa0w, uk0); uk0 = fmaf(w1.x, xb0x, uk0);
            uk0 = fmaf(w1.y, xb0y, uk0); uk0 = fmaf(w1.z, xb0z, uk0);
            uk0 = fmaf(w1.w, xb0w, uk0);
            float uk1 = w0.x * xa1x;
            uk1 = fmaf(w0.y, xa1y, uk1); uk1 = fmaf(w0.z, xa1z, uk1);
            uk1 = fmaf(w0.w, xa1w, uk1); uk1 = fmaf(w1.x, xb1x, uk1);
            uk1 = fmaf(w1.y, xb1y, uk1); uk1 = fmaf(w1.z, xb1z, uk1);
            uk1 = fmaf(w1.w, xb1w, uk1);
            u[0][k] = uk0; u[1][k] = uk1;
            if (!UNIFORM) {
                logit0 = fmaf(vsf[0][k], uk0, logit0);
                logit1 = fmaf(vsf[1][k], uk1, logit1);
            }
        }

        float c0, c1;
        if (UNIFORM) {
            c0 = c1 = 1.0f / 64.0f;
        } else {
            float m0 = logit0, m1 = logit1;
            #pragma unroll
            for (int d = 32; d >= 1; d >>= 1) {
                m0 = fmaxf(m0, __shfl_xor(m0, d, 64));
                m1 = fmaxf(m1, __shfl_xor(m1, d, 64));
            }
            float e0 = __expf(logit0 - m0);
            float e1 = __expf(logit1 - m1);
            float s0 = e0, s1 = e1;
            #pragma unroll
            for (int d = 32; d >= 1; d >>= 1) {
                s0 += __shfl_xor(s0, d, 64);
                s1 += __shfl_xor(s1, d, 64);
            }
            c0 = e0 / s0;
            c1 = e1 / s1;
        }

        #pragma unroll
        for (int k = 0; k < 16; ++k) {
            sacc[0][k] = fmaf(c0, u[0][k], sacc[0][k]);
            sacc[1][k] = fmaf(c1, u[1][k], sacc[1][k]);
        }
    }

    if (DIRECT) {
        #pragma unroll
        for (int l = 0; l < 2; ++l) {
            float4* sp = (float4*)s_out + (((size_t)chunk * 64 + (bbase + l)) * 64 + o) * 4;
            sp[0] = make_float4(sacc[l][0],  sacc[l][1],  sacc[l][2],  sacc[l][3]);
            sp[1] = make_float4(sacc[l][4],  sacc[l][5],  sacc[l][6],  sacc[l][7]);
            sp[2] = make_float4(sacc[l][8],  sacc[l][9],  sacc[l][10], sacc[l][11]);
            sp[3] = make_float4(sacc[l][12], sacc[l][13], sacc[l][14], sacc[l][15]);
        }
    } else {
        #pragma unroll
        for (int l = 0; l < 2; ++l) {
            float* sp = s_out + ((size_t)(bbase + l) * 64 + o) * 16;
            #pragma unroll
            for (int k = 0; k < 16; ++k) atomicAdd(sp + k, sacc[l][k]);
        }
    }
}

// Reduce NCHUNK chunk-partials per (b,o), then squash.
// MODE 0: Vsum=v; 1: Vsum+=v; 2: out=v.
template<int MODE>
__global__ __launch_bounds__(256)
void reduce_squash(const float* __restrict__ sp, float* __restrict__ Vs, float* __restrict__ out) {
    const int t = threadIdx.x;
    const int p = t >> 4;          // pair 0..15
    const int q = t & 15;          // chunk group 0..15
    const int pair = blockIdx.x * 16 + p;
    const int b = pair >> 6, o = pair & 63;

    float acc[16];
    #pragma unroll
    for (int k = 0; k < 16; ++k) acc[k] = 0.0f;

    const float4* base = (const float4*)sp;
    for (int c = q * (NCHUNK/16); c < (q + 1) * (NCHUNK/16); ++c) {
        const float4* pptr = base + (((size_t)c * 64 + b) * 64 + o) * 4;
        float4 v0 = pptr[0], v1 = pptr[1], v2 = pptr[2], v3 = pptr[3];
        acc[0] += v0.x; acc[1] += v0.y; acc[2]  += v0.z; acc[3]  += v0.w;
        acc[4] += v1.x; acc[5] += v1.y; acc[6]  += v1.z; acc[7]  += v1.w;
        acc[8] += v2.x; acc[9] += v2.y; acc[10] += v2.z; acc[11] += v2.w;
        acc[12] += v3.x; acc[13] += v3.y; acc[14] += v3.z; acc[15] += v3.w;
    }

    #pragma unroll
    for (int d = 1; d < 16; d <<= 1) {
        #pragma unroll
        for (int k = 0; k < 16; ++k) acc[k] += __shfl_xor(acc[k], d, 64);
    }

    if (q == 0) {
        float n2 = 0.0f;
        #pragma unroll
        for (int k = 0; k < 16; ++k) n2 = fmaf(acc[k], acc[k], n2);
        const float scale = n2 / (1.0f + n2) / sqrtf(n2 + 1e-7f);

        if (MODE == 0) {
            float4* vf = (float4*)Vs + (size_t)pair * 4;
            #pragma unroll
            for (int r = 0; r < 4; ++r)
                vf[r] = make_float4(scale * acc[r*4+0], scale * acc[r*4+1],
                                    scale * acc[r*4+2], scale * acc[r*4+3]);
        } else if (MODE == 1) {
            float4* vf = (float4*)Vs + (size_t)pair * 4;
            #pragma unroll
            for (int r = 0; r < 4; ++r) {
                float4 v = vf[r];
                v.x = fmaf(scale, acc[r*4+0], v.x); v.y = fmaf(scale, acc[r*4+1], v.y);
                v.z = fmaf(scale, acc[r*4+2], v.z); v.w = fmaf(scale, acc[r*4+3], v.w);
                vf[r] = v;
            }
        } else {
            float4* of = (float4*)out + (size_t)pair * 4;
            #pragma unroll
            for (int r = 0; r < 4; ++r)
                of[r] = make_float4(scale * acc[r*4+0], scale * acc[r*4+1],
                                    scale * acc[r*4+2], scale * acc[r*4+3]);
        }
    }
}

// Fallback squash for the atomic path.
template<int MODE>
__global__ __launch_bounds__(256)
void squash_k(float* __restrict__ s, float* __restrict__ Vsum, float* __restrict__ out) {
    const int t = blockIdx.x * blockDim.x + threadIdx.x;
    float4* sf = (float4*)s + t * 4;
    float4 qv[4];
    #pragma unroll
    for (int r = 0; r < 4; ++r) qv[r] = sf[r];
    float n2 = 0.0f;
    #pragma unroll
    for (int r = 0; r < 4; ++r)
        n2 = fmaf(qv[r].x, qv[r].x, fmaf(qv[r].y, qv[r].y, fmaf(qv[r].z, qv[r].z, fmaf(qv[r].w, qv[r].w, n2))));
    const float scale = n2 / (1.0f + n2) / sqrtf(n2 + 1e-7f);

    if (MODE == 0 || MODE == 1) {
        float4* vf = (float4*)Vsum + t * 4;
        #pragma unroll
        for (int r = 0; r < 4; ++r) {
            float4 v = (MODE == 1) ? vf[r] : make_float4(0.f, 0.f, 0.f, 0.f);
            v.x = fmaf(scale, qv[r].x, v.x); v.y = fmaf(scale, qv[r].y, v.y);
            v.z = fmaf(scale, qv[r].z, v.z); v.w = fmaf(scale, qv[r].w, v.w);
            vf[r] = v;
            sf[r] = make_float4(0.f, 0.f, 0.f, 0.f);
        }
    } else {
        float4* of = (float4*)out + t * 4;
        #pragma unroll
        for (int r = 0; r < 4; ++r)
            of[r] = make_float4(scale * qv[r].x, scale * qv[r].y, scale * qv[r].z, scale * qv[r].w);
    }
}

extern "C" void kernel_launch(void* const* d_in, const int* in_sizes, int n_in,
                              void* d_out, int out_size, void* d_ws, size_t ws_size,
                              hipStream_t stream) {
    const float* x = (const float*)d_in[0];   // [64,1152,8]
    const float* W = (const float*)d_in[1];   // [64,1152,16,8]
    float* out = (float*)d_out;               // [64,64,16]

    float* Vs = (float*)d_ws;                                  // 65536 floats
    float* sp = Vs + 65536;                                    // partials
    const size_t need = (65536ull + (size_t)NCHUNK * 64 * 64 * 16) * 4;

    dim3 grid(8 * NCHUNK), blk(256);

    if (ws_size >= need) {
        dim3 rg(256), rb(256);
        caps_route<true , true ><<<grid, blk, 0, stream>>>(x, W, nullptr, sp);
        reduce_squash<0><<<rg, rb, 0, stream>>>(sp, Vs, out);
        caps_route<false, true ><<<grid, blk, 0, stream>>>(x, W, Vs, sp);
        reduce_squash<1><<<rg, rb, 0, stream>>>(sp, Vs, out);
        caps_route<false, true ><<<grid, blk, 0, stream>>>(x, W, Vs, sp);
        reduce_squash<2><<<rg, rb, 0, stream>>>(sp, Vs, out);
    } else {
        float* s = sp;
        hipMemsetAsync(s, 0, 65536 * sizeof(float), stream);
        dim3 sg(16), sb(256);
        caps_route<true , false><<<grid, blk, 0, stream>>>(x, W, nullptr, s);
        squash_k<0><<<sg, sb, 0, stream>>>(s, Vs, out);
        caps_route<false, false><<<grid, blk, 0, stream>>>(x, W, Vs, s);
        squash_k<1><<<sg, sb, 0, stream>>>(s, Vs, out);
        caps_route<false, false><<<grid, blk, 0, stream>>>(x, W, Vs, s);
        squash_k<2><<<sg, sb, 0, stream>>>(s, Vs, out);
    }
}

// Round 6
// 126.957 us; speedup vs baseline: 2.5618x; 1.4748x over previous
//
#include <hip/hip_runtime.h>
#include <math.h>

// B=64, N_in=1152, K_in=8, N_out=64, K_out=16, ITER=3
// MFMA path: u-tiles C[k,b] = W-side(A) x x-side(B) via 16x16x32 bf16 MFMA,
// with fp32 fidelity from a (hi,lo)x(hi,lo) K-slot pack. No atomics, no W-LDS.

#define CTI 12        // i per chunk (MFMA path)
#define CNCH 96       // 1152 / CTI

typedef __attribute__((ext_vector_type(8))) short short8v;
typedef __attribute__((ext_vector_type(8))) unsigned short ushort8v;
typedef __attribute__((ext_vector_type(4))) float f32x4;

__device__ __forceinline__ unsigned short f2bf(float f) {   // RTNE
    unsigned u = __builtin_bit_cast(unsigned, f);
    u = u + 0x7FFFu + ((u >> 16) & 1u);
    return (unsigned short)(u >> 16);
}
__device__ __forceinline__ float bf2f(unsigned short h) {
    unsigned u = ((unsigned)h) << 16;
    return __builtin_bit_cast(float, u);
}

// W[o][i][k][j] f32  ->  Wp[i][o][p(hi/lo)][k][j] bf16
__global__ __launch_bounds__(256)
void w_xform(const float* __restrict__ W, unsigned short* __restrict__ Wp) {
    int tid = blockIdx.x * 256 + threadIdx.x;     // 1152*64*16 threads
    int k = tid & 15, o = (tid >> 4) & 63, i = tid >> 10;
    const float4* src = (const float4*)(W + (((size_t)o * 1152 + i) * 16 + k) * 8);
    float4 v0 = src[0], v1 = src[1];
    float vf[8] = {v0.x, v0.y, v0.z, v0.w, v1.x, v1.y, v1.z, v1.w};
    ushort8v hi, lo;
    #pragma unroll
    for (int j = 0; j < 8; ++j) {
        unsigned short h = f2bf(vf[j]);
        hi[j] = h;
        lo[j] = f2bf(vf[j] - bf2f(h));
    }
    size_t base = (((size_t)i * 64 + o) * 2) * 128 + (size_t)k * 8;
    *reinterpret_cast<ushort8v*>(Wp + base)       = hi;
    *reinterpret_cast<ushort8v*>(Wp + base + 128) = lo;
}

// x[b][i][j] f32 -> xp[i][p][b][j] bf16
__global__ __launch_bounds__(256)
void x_xform(const float* __restrict__ x, unsigned short* __restrict__ xp) {
    int tid = blockIdx.x * 256 + threadIdx.x;     // 1152*64 threads
    int b = tid & 63, i = tid >> 6;
    const float4* src = (const float4*)(x + ((size_t)b * 1152 + i) * 8);
    float4 v0 = src[0], v1 = src[1];
    float vf[8] = {v0.x, v0.y, v0.z, v0.w, v1.x, v1.y, v1.z, v1.w};
    ushort8v hi, lo;
    #pragma unroll
    for (int j = 0; j < 8; ++j) {
        unsigned short h = f2bf(vf[j]);
        hi[j] = h;
        lo[j] = f2bf(vf[j] - bf2f(h));
    }
    size_t base = ((size_t)i * 2) * 512 + (size_t)b * 8;
    *reinterpret_cast<ushort8v*>(xp + base)       = hi;
    *reinterpret_cast<ushort8v*>(xp + base + 512) = lo;
}

// Routing pass. Grid 384 = 4 btile x 96 chunk (XCD-swizzled: chunk%8 = bid%8).
// Block: 256 thr, 4 waves; wave wv owns o = wv*16..+15; lanes: col b=l&15, k-rows g=l>>4.
// A-frag (W-side [16k x 32slots]): lane reads Wp[i][o][g&1][l&15][0..7]  (16B, coalesced)
// B-frag (x-side [32slots x 16b]): lane reads xp[i][g>>1][btile*16+(l&15)][0..7]
// C[k,b] fp32 = full-precision u (hi/lo combos packed in K-slots).
template<int ROUTED>
__global__ __launch_bounds__(256, 2)
void caps_mfma(const unsigned short* __restrict__ Wp,
               const unsigned short* __restrict__ xp,
               const float* __restrict__ Vfp,
               float* __restrict__ spart) {
    __shared__ float mbuf[64];
    __shared__ float zbuf[64];
    const int t = threadIdx.x;
    const int wv = t >> 6, l = t & 63;
    const int bx = blockIdx.x;
    const int low = bx & 7, mm = bx >> 3;
    const int btile = mm & 3, chunk = (mm >> 2) * 8 + low;
    const int o0 = wv * 16;
    const int g = l >> 4, b15 = l & 15;

    f32x4 s[16];
    #pragma unroll
    for (int oo = 0; oo < 16; ++oo) s[oo] = (f32x4){0.f, 0.f, 0.f, 0.f};

    for (int ii = 0; ii < CTI; ++ii) {
        const int i = chunk * CTI + ii;
        const unsigned short* wbase = Wp + (size_t)i * (64 * 256);
        short8v Bf = *reinterpret_cast<const short8v*>(
            xp + (((size_t)i * 2 + (l >> 5)) * 64 + btile * 16 + b15) * 8);

        if (!ROUTED) {
            // uniform pass: c = 1/64 -> accumulate u straight into C across i
            #pragma unroll
            for (int oo = 0; oo < 16; ++oo) {
                short8v Af = *reinterpret_cast<const short8v*>(
                    wbase + (((size_t)(o0 + oo) * 2 + (g & 1)) * 128 + b15 * 8));
                s[oo] = __builtin_amdgcn_mfma_f32_16x16x32_bf16(Af, Bf, s[oo], 0, 0, 0);
            }
        } else {
            f32x4 u[16];
            float lg[16];
            #pragma unroll
            for (int oo = 0; oo < 16; ++oo) {
                short8v Af = *reinterpret_cast<const short8v*>(
                    wbase + (((size_t)(o0 + oo) * 2 + (g & 1)) * 128 + b15 * 8));
                f32x4 zz = {0.f, 0.f, 0.f, 0.f};
                u[oo] = __builtin_amdgcn_mfma_f32_16x16x32_bf16(Af, Bf, zz, 0, 0, 0);
                f32x4 Vf = *reinterpret_cast<const f32x4*>(
                    Vfp + (((size_t)btile * 64 + o0 + oo) * 64 + l) * 4);
                float p = u[oo][0] * Vf[0];
                p = fmaf(u[oo][1], Vf[1], p);
                p = fmaf(u[oo][2], Vf[2], p);
                p = fmaf(u[oo][3], Vf[3], p);
                p += __shfl_xor(p, 16, 64);     // sum over k-groups
                p += __shfl_xor(p, 32, 64);
                lg[oo] = p;                     // logit[b=b15, o0+oo], replicated
            }
            // cross-wave softmax over all 64 o (two tiny LDS exchanges)
            float mp = lg[0];
            #pragma unroll
            for (int oo = 1; oo < 16; ++oo) mp = fmaxf(mp, lg[oo]);
            if (l < 16) mbuf[o0 + l] = mp;
            __syncthreads();
            float mg = fmaxf(fmaxf(mbuf[b15], mbuf[16 + b15]),
                             fmaxf(mbuf[32 + b15], mbuf[48 + b15]));
            float sp = 0.f;
            #pragma unroll
            for (int oo = 0; oo < 16; ++oo) { lg[oo] = __expf(lg[oo] - mg); sp += lg[oo]; }
            if (l < 16) zbuf[o0 + l] = sp;
            __syncthreads();
            float Z = (zbuf[b15] + zbuf[16 + b15]) + (zbuf[32 + b15] + zbuf[48 + b15]);
            float rz = 1.0f / Z;
            #pragma unroll
            for (int oo = 0; oo < 16; ++oo) {
                float c = lg[oo] * rz;          // c[b, o0+oo] -- lane-local (col = b)
                s[oo][0] = fmaf(c, u[oo][0], s[oo][0]);
                s[oo][1] = fmaf(c, u[oo][1], s[oo][1]);
                s[oo][2] = fmaf(c, u[oo][2], s[oo][2]);
                s[oo][3] = fmaf(c, u[oo][3], s[oo][3]);
            }
        }
    }

    const float fin = ROUTED ? 1.0f : (1.0f / 64.0f);
    #pragma unroll
    for (int oo = 0; oo < 16; ++oo) {
        f32x4 vv = s[oo] * fin;
        *reinterpret_cast<f32x4*>(spart +
            ((((size_t)chunk * 4 + btile) * 64 + (o0 + oo)) * 64 + l) * 4) = vv;
    }
}

// Sum 96 chunk-partials (frag-ordered), squash, update Vfp / write out.
// MODE 0: Vfp=v; 1: Vfp+=v; 2: out=v.  Grid 64x256; thread=(btile,o,lane).
template<int MODE>
__global__ __launch_bounds__(256)
void reduce2(const float* __restrict__ spart, float* __restrict__ Vfp,
             float* __restrict__ out) {
    const int tid = blockIdx.x * 256 + threadIdx.x;    // 16384
    const int l = tid & 63, o = (tid >> 6) & 63, btile = tid >> 12;
    f32x4 acc = {0.f, 0.f, 0.f, 0.f};
    const float* base = spart + (((size_t)btile * 64 + o) * 64 + l) * 4;
    for (int c = 0; c < CNCH; ++c)
        acc += *reinterpret_cast<const f32x4*>(base + (size_t)c * 65536);
    float n2 = acc[0]*acc[0] + acc[1]*acc[1] + acc[2]*acc[2] + acc[3]*acc[3];
    n2 += __shfl_xor(n2, 16, 64);
    n2 += __shfl_xor(n2, 32, 64);
    const float scale = n2 / (1.0f + n2) / sqrtf(n2 + 1e-7f);
    f32x4 v = acc * scale;
    float* vp = Vfp + (((size_t)btile * 64 + o) * 64 + l) * 4;
    if (MODE == 0) {
        *reinterpret_cast<f32x4*>(vp) = v;
    } else if (MODE == 1) {
        f32x4 old = *reinterpret_cast<const f32x4*>(vp);
        *reinterpret_cast<f32x4*>(vp) = old + v;
    } else {
        const int b = btile * 16 + (l & 15), gq = l >> 4;
        *reinterpret_cast<f32x4*>(out + (((size_t)b * 64 + o) * 16 + gq * 4)) = v;
    }
}

// ------------------------- round-5 fallback (proven) -------------------------
#define FTI 18
#define FNCH 64

typedef const __attribute__((address_space(1))) unsigned int gu32;
typedef __attribute__((address_space(3))) unsigned int lu32;

__device__ __forceinline__ void load_lds16(const float4* gp, float4* lp) {
    __builtin_amdgcn_global_load_lds((gu32*)gp, (lu32*)lp, 16, 0, 0);
}
__device__ __forceinline__ float rfl(float v) {
    return __builtin_bit_cast(float, __builtin_amdgcn_readfirstlane(__builtin_bit_cast(int, v)));
}

template<bool UNIFORM>
__global__ __launch_bounds__(256, 2)
void caps_route_fb(const float* __restrict__ x, const float* __restrict__ W,
                   const float* __restrict__ Vsum, float* __restrict__ s_out) {
    __shared__ float4 wlds[2][2048];
    __shared__ float4 xlds[8 * FTI * 2];
    const int t = threadIdx.x;
    const int w = t >> 6, o = t & 63;
    const int chunk = blockIdx.x % FNCH, bblk = blockIdx.x / FNCH;
    const int i0 = chunk * FTI, bbase = bblk * 8 + w * 2;
    const float4* __restrict__ xg = (const float4*)x;
    const float4* __restrict__ Wg = (const float4*)W;
    for (int e = t; e < 8 * FTI * 2; e += 256) {
        int bb = e / (FTI * 2), r = e % (FTI * 2);
        xlds[e] = xg[((bblk * 8 + bb) * 1152 + i0 + (r >> 1)) * 2 + (r & 1)];
    }
    const float4* wsrc = Wg + (size_t)o * 36864 + (size_t)i0 * 32 + w * 8;
    #pragma unroll
    for (int r = 0; r < 8; ++r) load_lds16(wsrc + r, &wlds[0][(w * 8 + r) * 64]);
    float vsf[2][16];
    if (!UNIFORM) {
        const float4* vg = (const float4*)Vsum;
        #pragma unroll
        for (int ll = 0; ll < 2; ++ll)
            #pragma unroll
            for (int q = 0; q < 4; ++q) {
                float4 v = vg[((size_t)(bbase + ll) * 64 + o) * 4 + q];
                vsf[ll][q*4+0] = v.x; vsf[ll][q*4+1] = v.y;
                vsf[ll][q*4+2] = v.z; vsf[ll][q*4+3] = v.w;
            }
    }
    float sacc[2][16];
    #pragma unroll
    for (int ll = 0; ll < 2; ++ll)
        #pragma unroll
        for (int k = 0; k < 16; ++k) sacc[ll][k] = 0.0f;
    for (int ii = 0; ii < FTI; ++ii) {
        const int cur = ii & 1;
        __syncthreads();
        if (ii + 1 < FTI) {
            const float4* ws = wsrc + (size_t)(ii + 1) * 32;
            #pragma unroll
            for (int r = 0; r < 8; ++r) load_lds16(ws + r, &wlds[cur ^ 1][(w * 8 + r) * 64]);
        }
        float4 A0 = xlds[(w*2+0)*(FTI*2) + ii*2 + 0];
        float4 B0 = xlds[(w*2+0)*(FTI*2) + ii*2 + 1];
        float4 A1 = xlds[(w*2+1)*(FTI*2) + ii*2 + 0];
        float4 B1 = xlds[(w*2+1)*(FTI*2) + ii*2 + 1];
        float xa0x=rfl(A0.x),xa0y=rfl(A0.y),xa0z=rfl(A0.z),xa0w=rfl(A0.w);
        float xb0x=rfl(B0.x),xb0y=rfl(B0.y),xb0z=rfl(B0.z),xb0w=rfl(B0.w);
        float xa1x=rfl(A1.x),xa1y=rfl(A1.y),xa1z=rfl(A1.z),xa1w=rfl(A1.w);
        float xb1x=rfl(B1.x),xb1y=rfl(B1.y),xb1z=rfl(B1.z),xb1w=rfl(B1.w);
        const float4* wb = wlds[cur];
        float u[2][16];
        float logit0 = 0.0f, logit1 = 0.0f;
        #pragma unroll
        for (int k = 0; k < 16; ++k) {
            float4 w0 = wb[(2*k  )*64 + o];
            float4 w1 = wb[(2*k+1)*64 + o];
            float uk0 = w0.x*xa0x; uk0=fmaf(w0.y,xa0y,uk0); uk0=fmaf(w0.z,xa0z,uk0);
            uk0=fmaf(w0.w,xa0w,uk0); uk0=fmaf(w1.x,xb0x,uk0); uk0=fmaf(w1.y,xb0y,uk0);
            uk0=fmaf(w1.z,xb0z,uk0); uk0=fmaf(w1.w,xb0w,uk0);
            float uk1 = w0.x*xa1x; uk1=fmaf(w0.y,xa1y,uk1); uk1=fmaf(w0.z,xa1z,uk1);
            uk1=fmaf(w0.w,xa1w,uk1); uk1=fmaf(w1.x,xb1x,uk1); uk1=fmaf(w1.y,xb1y,uk1);
            uk1=fmaf(w1.z,xb1z,uk1); uk1=fmaf(w1.w,xb1w,uk1);
            u[0][k]=uk0; u[1][k]=uk1;
            if (!UNIFORM) { logit0=fmaf(vsf[0][k],uk0,logit0); logit1=fmaf(vsf[1][k],uk1,logit1); }
        }
        float c0, c1;
        if (UNIFORM) { c0 = c1 = 1.0f/64.0f; }
        else {
            float m0=logit0, m1=logit1;
            #pragma unroll
            for (int d=32; d>=1; d>>=1) { m0=fmaxf(m0,__shfl_xor(m0,d,64)); m1=fmaxf(m1,__shfl_xor(m1,d,64)); }
            float e0=__expf(logit0-m0), e1=__expf(logit1-m1);
            float s0=e0, s1=e1;
            #pragma unroll
            for (int d=32; d>=1; d>>=1) { s0+=__shfl_xor(s0,d,64); s1+=__shfl_xor(s1,d,64); }
            c0=e0/s0; c1=e1/s1;
        }
        #pragma unroll
        for (int k = 0; k < 16; ++k) {
            sacc[0][k]=fmaf(c0,u[0][k],sacc[0][k]);
            sacc[1][k]=fmaf(c1,u[1][k],sacc[1][k]);
        }
    }
    #pragma unroll
    for (int ll = 0; ll < 2; ++ll) {
        float4* sp = (float4*)s_out + (((size_t)chunk * 64 + (bbase + ll)) * 64 + o) * 4;
        sp[0]=make_float4(sacc[ll][0],sacc[ll][1],sacc[ll][2],sacc[ll][3]);
        sp[1]=make_float4(sacc[ll][4],sacc[ll][5],sacc[ll][6],sacc[ll][7]);
        sp[2]=make_float4(sacc[ll][8],sacc[ll][9],sacc[ll][10],sacc[ll][11]);
        sp[3]=make_float4(sacc[ll][12],sacc[ll][13],sacc[ll][14],sacc[ll][15]);
    }
}

template<int MODE>
__global__ __launch_bounds__(256)
void reduce_squash_fb(const float* __restrict__ sp, float* __restrict__ Vs, float* __restrict__ out) {
    const int t = threadIdx.x;
    const int p = t >> 4, q = t & 15;
    const int pair = blockIdx.x * 16 + p;
    const int b = pair >> 6, o = pair & 63;
    float acc[16];
    #pragma unroll
    for (int k = 0; k < 16; ++k) acc[k] = 0.0f;
    const float4* base = (const float4*)sp;
    for (int c = q * (FNCH/16); c < (q + 1) * (FNCH/16); ++c) {
        const float4* pptr = base + (((size_t)c * 64 + b) * 64 + o) * 4;
        float4 v0=pptr[0],v1=pptr[1],v2=pptr[2],v3=pptr[3];
        acc[0]+=v0.x;acc[1]+=v0.y;acc[2]+=v0.z;acc[3]+=v0.w;
        acc[4]+=v1.x;acc[5]+=v1.y;acc[6]+=v1.z;acc[7]+=v1.w;
        acc[8]+=v2.x;acc[9]+=v2.y;acc[10]+=v2.z;acc[11]+=v2.w;
        acc[12]+=v3.x;acc[13]+=v3.y;acc[14]+=v3.z;acc[15]+=v3.w;
    }
    #pragma unroll
    for (int d = 1; d < 16; d <<= 1)
        #pragma unroll
        for (int k = 0; k < 16; ++k) acc[k] += __shfl_xor(acc[k], d, 64);
    if (q == 0) {
        float n2 = 0.0f;
        #pragma unroll
        for (int k = 0; k < 16; ++k) n2 = fmaf(acc[k], acc[k], n2);
        const float scale = n2 / (1.0f + n2) / sqrtf(n2 + 1e-7f);
        if (MODE == 0) {
            float4* vf = (float4*)Vs + (size_t)pair * 4;
            #pragma unroll
            for (int r = 0; r < 4; ++r)
                vf[r] = make_float4(scale*acc[r*4+0],scale*acc[r*4+1],scale*acc[r*4+2],scale*acc[r*4+3]);
        } else if (MODE == 1) {
            float4* vf = (float4*)Vs + (size_t)pair * 4;
            #pragma unroll
            for (int r = 0; r < 4; ++r) {
                float4 v = vf[r];
                v.x=fmaf(scale,acc[r*4+0],v.x); v.y=fmaf(scale,acc[r*4+1],v.y);
                v.z=fmaf(scale,acc[r*4+2],v.z); v.w=fmaf(scale,acc[r*4+3],v.w);
                vf[r] = v;
            }
        } else {
            float4* of = (float4*)out + (size_t)pair * 4;
            #pragma unroll
            for (int r = 0; r < 4; ++r)
                of[r] = make_float4(scale*acc[r*4+0],scale*acc[r*4+1],scale*acc[r*4+2],scale*acc[r*4+3]);
        }
    }
}
// -----------------------------------------------------------------------------

extern "C" void kernel_launch(void* const* d_in, const int* in_sizes, int n_in,
                              void* d_out, int out_size, void* d_ws, size_t ws_size,
                              hipStream_t stream) {
    const float* x = (const float*)d_in[0];   // [64,1152,8]
    const float* W = (const float*)d_in[1];   // [64,1152,16,8]
    float* out = (float*)d_out;               // [64,64,16]

    float* Vfp = (float*)d_ws;                                 // 65536 f32 (frag-ordered Vsum)
    float* spart = Vfp + 65536;                                // CNCH*65536 f32
    unsigned short* Wp = (unsigned short*)(spart + (size_t)CNCH * 65536);
    unsigned short* xpp = Wp + (size_t)1152 * 64 * 256;
    const size_t need_full = ((size_t)65536 + (size_t)CNCH * 65536) * 4
                           + ((size_t)1152 * 64 * 256 + (size_t)1152 * 2 * 64 * 8) * 2;

    if (ws_size >= need_full) {
        w_xform<<<4608, 256, 0, stream>>>(W, Wp);
        x_xform<<<288, 256, 0, stream>>>(x, xpp);
        caps_mfma<0><<<384, 256, 0, stream>>>(Wp, xpp, Vfp, spart);
        reduce2<0><<<64, 256, 0, stream>>>(spart, Vfp, out);
        caps_mfma<1><<<384, 256, 0, stream>>>(Wp, xpp, Vfp, spart);
        reduce2<1><<<64, 256, 0, stream>>>(spart, Vfp, out);
        caps_mfma<1><<<384, 256, 0, stream>>>(Wp, xpp, Vfp, spart);
        reduce2<2><<<64, 256, 0, stream>>>(spart, Vfp, out);
    } else {
        // proven round-5 path (needs ~17 MB)
        float* Vs = (float*)d_ws;
        float* sp = Vs + 65536;
        dim3 grid(8 * FNCH), blk(256);
        dim3 rg(256), rb(256);
        caps_route_fb<true ><<<grid, blk, 0, stream>>>(x, W, nullptr, sp);
        reduce_squash_fb<0><<<rg, rb, 0, stream>>>(sp, Vs, out);
        caps_route_fb<false><<<grid, blk, 0, stream>>>(x, W, Vs, sp);
        reduce_squash_fb<1><<<rg, rb, 0, stream>>>(sp, Vs, out);
        caps_route_fb<false><<<grid, blk, 0, stream>>>(x, W, Vs, sp);
        reduce_squash_fb<2><<<rg, rb, 0, stream>>>(sp, Vs, out);
    }
}